// Round 19
// baseline (261.219 us; speedup 1.0000x reference)
//
#include <hip/hip_runtime.h>

// RbfNet on MI355X — round 19: layer0 gather de-atomized via the r11 commute trick.
// r17/r18 showed layer0_gemm pinned at ~52us regardless of occupancy/structure; the
// distinguishing feature vs the faster conv kernels was the contended LDS atomicAdd
// gather. Now: U0L0[n,288] bf16 = [x@cW0 (p-major 8x32) | x@fW0 (32)] precomputed in
// fill_prep (3rd block range), and layer0's conv = pair-packed gather (128B span,
// 2 edges/wave-load, shfl_xor merges, ZERO atomics) + fused UL1 MFMA tail (r18 shape).
// Structure: UL[j] = [x_j @ cW (p-major, 512) | x_j @ fW (64)]; conv(x)[i] =
// sum_e w0*U[j,p] + w1*U[j,p+1]; layer3 via T[j][p] = ansc2[j] @ cW3[p] (fused in conv2).
// Edge record (4B): j(15b) | p(3b) | round(w0*16383)(14b); w1 = 1-w0. Self-edges dropped.

#define CAP 48

typedef __attribute__((ext_vector_type(8))) short short8;
typedef __attribute__((ext_vector_type(4))) short short4v;
typedef __attribute__((ext_vector_type(4))) float f32x4;

__device__ __forceinline__ short bf16s(float f) {   // fp32 -> bf16 RNE
  unsigned u = __float_as_uint(f);
  return (short)((u + 0x7FFF + ((u >> 16) & 1)) >> 16);
}
__device__ __forceinline__ float b2f(unsigned short s) {
  return __uint_as_float(((unsigned)s) << 16);
}

// ---------- fused: edge-bucket build | WTul prep | U0L0 prep (3 block ranges) ----------
__global__ void fill_prep(const float* __restrict__ dist,
                          const int* __restrict__ fi, const int* __restrict__ fj,
                          int* __restrict__ cnt, int* __restrict__ jw, int nE,
                          const float* __restrict__ cW1, const float* __restrict__ fW1,
                          const float* __restrict__ cW2, const float* __restrict__ fW2,
                          short* __restrict__ wt1, short* __restrict__ wt2,
                          const float* __restrict__ X,    // [n,4]
                          const float* __restrict__ cW0,  // [8,4,32]
                          const float* __restrict__ fW0,  // [4,32]
                          unsigned short* __restrict__ U0, int n,
                          int fillBlocks, int prepBlocks) {
  if ((int)blockIdx.x < fillBlocks) {
    int e = blockIdx.x * blockDim.x + threadIdx.x;
    if (e >= nE) return;
    int i = fi[e], j = fj[e];
    if (i == j) return;                  // centerIgnore
    float d = fminf(1.0f, fmaxf(-1.0f, dist[e]));
    float u = (d + 1.0f) * 3.5f;         // hat centers: spacing 2/7
    int p = min((int)u, 6);
    float w0 = 1.0f - (u - (float)p);
    int wq = (int)(w0 * 16383.0f + 0.5f);
    int pos = atomicAdd(&cnt[i], 1);
    if (pos < CAP)
      jw[(size_t)i * CAP + pos] = j | (p << 15) | (wq << 18);
  } else if ((int)blockIdx.x < fillBlocks + prepBlocks) {
    int idx = ((int)blockIdx.x - fillBlocks) * blockDim.x + threadIdx.x;
    if (idx >= 2 * 576 * 64) return;
    int sel = idx / (576 * 64);
    int r = idx - sel * (576 * 64);
    int col = r >> 6, ch = r & 63;
    const float* cW = sel ? cW2 : cW1;
    const float* fW = sel ? fW2 : fW1;
    float v;
    if (col < 512) {
      int p = col >> 6, co = col & 63;
      v = cW[((size_t)p * 64 + ch) * 64 + co];
    } else {
      v = fW[(size_t)ch * 64 + (col - 512)];
    }
    (sel ? wt2 : wt1)[(size_t)col * 64 + ch] = bf16s(v);
  } else {
    // U0L0: [n,288] bf16; c<256: p=c>>5,co=c&31 -> x@cW0[p]; c>=256 -> x@fW0
    int idx = ((int)blockIdx.x - fillBlocks - prepBlocks) * blockDim.x + threadIdx.x;
    if (idx >= n * 288) return;
    int i = idx / 288, c = idx - i * 288;
    const float* x = X + (size_t)i * 4;
    float s = 0.0f;
    if (c < 256) {
      int p = c >> 5, co = c & 31;
      #pragma unroll
      for (int k = 0; k < 4; ++k) s = fmaf(x[k], cW0[((size_t)p * 4 + k) * 32 + co], s);
    } else {
      int co = c - 256;
      #pragma unroll
      for (int k = 0; k < 4; ++k) s = fmaf(x[k], fW0[(size_t)k * 32 + co], s);
    }
    U0[(size_t)i * 288 + c] = (unsigned short)bf16s(s);
  }
}

// ---------- FUSED layer0 + gemm_ul1: 1024 threads, wave-per-node, NO LDS atomics ----------
__global__ __launch_bounds__(1024) void layer0_gemm(
    const unsigned short* __restrict__ U0,  // [n,288] bf16 (p-major conv ++ lin)
    const int* __restrict__ cnt, const int* __restrict__ jw,
    const float* __restrict__ cb0, const float* __restrict__ fb0,
    const short* __restrict__ WTul,   // [576,64] bf16 layer-1 weights (L2-resident)
    unsigned short* __restrict__ UL, int n) {
  __shared__ __align__(16) unsigned short sXa[16 * 64];   // ansc0 tile, bf16
  __shared__ __align__(16) short sUL[16 * 584];           // UL staging
  const int tid = threadIdx.x;
  const int w = tid >> 6;                 // wave 0..15, owns node w
  const int lane = tid & 63;
  const int grp = lane >> 5;              // 0: even edges, 1: odd edges
  const int gl = lane & 31;               // uint index within the 128B span
  const int nodeBase = blockIdx.x * 16;
  const int i = nodeBase + w;
  const bool valid = (i < n);
  const int ic = valid ? i : 0;

  int rec = jw[(size_t)ic * CAP + (lane < CAP ? lane : 0)];
  const int m = valid ? min(cnt[ic], CAP) : 0;
  const int mc = m - 1;
  float accLo = 0.0f, accHi = 0.0f;       // conv channels 2*(gl&15), +1 (per role)
  for (int q0 = 0; q0 < m; q0 += 16) {    // 16 edges per round, 2 per load slot
    unsigned raw[8];
    float ws[8];
    #pragma unroll
    for (int k = 0; k < 8; ++k) {         // issue all 8 loads before consuming
      int eA = q0 + 2 * k;
      int vA = __builtin_amdgcn_readlane(rec, min(eA, mc));
      int vB = __builtin_amdgcn_readlane(rec, min(eA + 1, mc));
      int v = grp ? vB : vA;
      int j = v & 0x7FFF;
      int p = (v >> 15) & 7;
      float w0 = (float)((unsigned)v >> 18) * (1.0f / 16383.0f);
      float wgt = (gl < 16) ? w0 : (1.0f - w0);
      ws[k] = (eA + grp < m) ? wgt : 0.0f;
      // 128B span = U0[j, p*32 .. p*32+63] (u0 32ch || u1 32ch), uint gl covers 2 ch
      raw[k] = ((const unsigned*)(U0 + (size_t)j * 288 + p * 32))[gl];
    }
    #pragma unroll
    for (int k = 0; k < 8; ++k) {
      accLo = fmaf(ws[k], __uint_as_float(raw[k] << 16), accLo);
      accHi = fmaf(ws[k], __uint_as_float(raw[k] & 0xFFFF0000u), accHi);
    }
  }
  accLo += __shfl_xor(accLo, 16, 64);     // merge u0/u1 roles
  accHi += __shfl_xor(accHi, 16, 64);
  accLo += __shfl_xor(accLo, 32, 64);     // merge even/odd edge groups
  accHi += __shfl_xor(accHi, 32, 64);
  if (lane < 16) {                        // lane l holds conv ch-pair (2l, 2l+1)
    const int l = lane;
    float c0v = fmaxf(accLo + cb0[2 * l], 0.0f);      // -> out ch 32+2l
    float c1v = fmaxf(accHi + cb0[2 * l + 1], 0.0f);
    unsigned lr = ((const unsigned*)(U0 + (size_t)ic * 288 + 256))[l];
    float l0 = fmaxf(__uint_as_float(lr << 16) + fb0[2 * l], 0.0f);          // out ch 2l
    float l1 = fmaxf(__uint_as_float(lr & 0xFFFF0000u) + fb0[2 * l + 1], 0.0f);
    unsigned* row = (unsigned*)(sXa + w * 64);
    row[l] = (unsigned)(unsigned short)bf16s(l0) | ((unsigned)(unsigned short)bf16s(l1) << 16);
    row[16 + l] = (unsigned)(unsigned short)bf16s(c0v) | ((unsigned)(unsigned short)bf16s(c1v) << 16);
  }
  __syncthreads();

  // ---- gemm tile: UL[16,576] = sXa[16,64] @ WTul^T; wave w does tiles w, w+16, w+32
  const int mrow = lane & 15;
  const int quad = lane >> 4;
  short8 b0 = *(const short8*)(sXa + mrow * 64 + quad * 8);
  short8 b1 = *(const short8*)(sXa + mrow * 64 + quad * 8 + 32);
  for (int t = w; t < 36; t += 16) {
    const short* aBase = WTul + (size_t)(t * 16 + mrow) * 64 + quad * 8;
    short8 a0 = *(const short8*)(aBase);
    short8 a1 = *(const short8*)(aBase + 32);
    f32x4 acc = {0, 0, 0, 0};
    acc = __builtin_amdgcn_mfma_f32_16x16x32_bf16(a0, b0, acc, 0, 0, 0);
    acc = __builtin_amdgcn_mfma_f32_16x16x32_bf16(a1, b1, acc, 0, 0, 0);
    short4v pk;
    #pragma unroll
    for (int reg = 0; reg < 4; ++reg) pk[reg] = bf16s(acc[reg]);
    *(short4v*)(sUL + mrow * 584 + t * 16 + quad * 4) = pk;
  }
  __syncthreads();
  // ---- coalesced store: 1024 threads cover 16 rows x 72 chunks of 16B
  const int r = tid >> 6;
  const int c0 = tid & 63;
  if (nodeBase + r < n) {
    unsigned short* dst = UL + (size_t)(nodeBase + r) * 576;
    #pragma unroll
    for (int chunk = c0; chunk < 72; chunk += 64)
      *(short8*)(dst + chunk * 8) = *(const short8*)(sUL + r * 584 + chunk * 8);
  }
}

// ---------- dense MFMA GEMM: UL[n,576] = Xb[n,64] @ WTul^T (layer 2) ----------
__global__ __launch_bounds__(256) void gemm_ul(
    const unsigned short* __restrict__ Xb,  // [n,64] bf16
    const short* __restrict__ WTul,         // [576,64] bf16 (L2-resident)
    unsigned short* __restrict__ UL, int n) {
  __shared__ short sUL[16 * 584];
  const int lane = threadIdx.x & 63;
  const int w = threadIdx.x >> 6;
  const int mrow = lane & 15;
  const int quad = lane >> 4;
  const int nodeBase = blockIdx.x * 16;
  const int bnode = min(nodeBase + mrow, n - 1);
  const unsigned short* bBase = Xb + (size_t)bnode * 64 + quad * 8;
  short8 b0 = *(const short8*)(bBase);
  short8 b1 = *(const short8*)(bBase + 32);
  #pragma unroll
  for (int t = 0; t < 9; ++t) {
    const int ct = w * 9 + t;
    const short* aBase = WTul + (size_t)(ct * 16 + mrow) * 64 + quad * 8;
    short8 a0 = *(const short8*)(aBase);
    short8 a1 = *(const short8*)(aBase + 32);
    f32x4 acc = {0, 0, 0, 0};
    acc = __builtin_amdgcn_mfma_f32_16x16x32_bf16(a0, b0, acc, 0, 0, 0);
    acc = __builtin_amdgcn_mfma_f32_16x16x32_bf16(a1, b1, acc, 0, 0, 0);
    short4v pk;
    #pragma unroll
    for (int reg = 0; reg < 4; ++reg) pk[reg] = bf16s(acc[reg]);
    *(short4v*)(sUL + mrow * 584 + ct * 16 + quad * 4) = pk;
  }
  __syncthreads();
  const int r = threadIdx.x >> 4;
  const int c0 = threadIdx.x & 15;
  if (nodeBase + r < n) {
    unsigned short* dst = UL + (size_t)(nodeBase + r) * 576;
    #pragma unroll
    for (int chunk = c0; chunk < 72; chunk += 16)
      *(short8*)(dst + chunk * 8) = *(const short8*)(sUL + r * 584 + chunk * 8);
  }
}

// ---------- conv gather: wave per node; ONE uint load per edge (256B span = u0|u1) ----------
template <bool HAS_RES, bool STORE_ANS, bool COMPUTE_T>
__global__ __launch_bounds__(256) void conv_gather(
    const unsigned short* __restrict__ UL,  // [n,576] bf16
    const int* __restrict__ cnt, const int* __restrict__ jw,
    const float* __restrict__ cb, const float* __restrict__ fb,
    const float* __restrict__ resid,        // fp32 [n,64] or null
    const float* __restrict__ cW3,          // [8,64,2] (only if COMPUTE_T)
    float* __restrict__ T,                  // [n,16] fp32 (only if COMPUTE_T)
    float* __restrict__ outAns,             // fp32 [n,64] or null
    unsigned short* __restrict__ outAnsc, int n) {  // bf16 [n,64]
  const int lane = threadIdx.x & 63;
  const int half = lane >> 5;               // 0 -> u0 (w0), 1 -> u1 (w1)
  const int pl = lane & 31;                 // channel-pair index
  const int i = (blockIdx.x * blockDim.x + threadIdx.x) >> 6;
  if (i >= n) return;
  int rec = jw[(size_t)i * CAP + (lane < CAP ? lane : 0)];  // lane q holds record q
  const int m = min(cnt[i], CAP);
  const int mc = m - 1;                     // waste-slot clamp target (real record)
  const unsigned short* ULrow = UL + (size_t)i * 576;
  const unsigned Lraw = ((const unsigned*)(ULrow + 512))[pl];
  float rv0 = 0.0f, rv1 = 0.0f;
  if (HAS_RES) {
    float2 rv = *(const float2*)(resid + (size_t)i * 64 + 2 * pl);
    rv0 = rv.x; rv1 = rv.y;
  }
  float accLo = 0.0f, accHi = 0.0f;         // channels 2*pl, 2*pl+1 of this half
  for (int q0 = 0; q0 < m; q0 += 16) {
    unsigned raw[16];
    float w0s[16];
    #pragma unroll
    for (int k = 0; k < 16; ++k) {          // issue all 16 loads before consuming
      int v = __builtin_amdgcn_readlane(rec, min(q0 + k, mc));
      int j = v & 0x7FFF;                   // real record -> in-bounds
      int p = (v >> 15) & 7;
      w0s[k] = (float)((unsigned)v >> 18) * (1.0f / 16383.0f);
      raw[k] = ((const unsigned*)(UL + (size_t)j * 576 + p * 64))[lane];
    }
    #pragma unroll
    for (int k = 0; k < 16; ++k) {
      bool ok = (q0 + k < m);
      float w = half ? (1.0f - w0s[k]) : w0s[k];
      w = ok ? w : 0.0f;
      accLo = fmaf(w, __uint_as_float(raw[k] << 16), accLo);
      accHi = fmaf(w, __uint_as_float(raw[k] & 0xFFFF0000u), accHi);
    }
  }
  accLo += __shfl_xor(accLo, 32, 64);       // merge u0/u1 halves
  accHi += __shfl_xor(accHi, 32, 64);
  if (half == 0) {                          // lanes 0-31 do the epilogue
    const int c0i = 2 * pl, c1i = c0i + 1;
    float L0 = __uint_as_float(Lraw << 16);
    float L1 = __uint_as_float(Lraw & 0xFFFF0000u);
    float o0 = accLo + L0 + cb[c0i] + fb[c0i] + rv0;
    float o1 = accHi + L1 + cb[c1i] + fb[c1i] + rv1;
    if (STORE_ANS)
      *(float2*)(outAns + (size_t)i * 64 + c0i) = make_float2(o0, o1);
    unsigned short xb0 = (unsigned short)bf16s(fmaxf(o0, 0.0f));
    unsigned short xb1 = (unsigned short)bf16s(fmaxf(o1, 0.0f));
    ((unsigned*)(outAnsc + (size_t)i * 64))[pl] = (unsigned)xb0 | ((unsigned)xb1 << 16);
    if (COMPUTE_T) {
      float x0 = b2f(xb0), x1 = b2f(xb1);
      float c[16];
      #pragma unroll
      for (int t = 0; t < 16; ++t) {
        const float* wrow = cW3 + ((size_t)(t >> 1) * 64) * 2 + (t & 1);
        c[t] = x0 * wrow[c0i * 2] + x1 * wrow[c1i * 2];
      }
      #pragma unroll
      for (int off = 16; off > 0; off >>= 1) {   // butterfly within lanes 0-31
        #pragma unroll
        for (int t = 0; t < 16; ++t) c[t] += __shfl_xor(c[t], off, 64);
      }
      if (pl == 0) {
        float* tr = T + (size_t)i * 16;
        #pragma unroll
        for (int t = 0; t < 16; ++t) tr[t] = c[t];
      }
    }
  }
}

// ---------- layer 3: wave per node, lane = edge; 16B/edge from T; + lin; reduce ----------
__global__ __launch_bounds__(256, 4) void layer3_kernel(
    const unsigned short* __restrict__ Xb,  // ansc2 [n,64] bf16
    const float* __restrict__ T,            // [n,16] fp32
    const int* __restrict__ cnt, const int* __restrict__ jw,
    const float* __restrict__ cb3, const float* __restrict__ fb3,
    const float* __restrict__ fW3,          // [64,2]
    float* __restrict__ out, int n) {
  const int lane = threadIdx.x & 63;
  const int i = (blockIdx.x * blockDim.x + threadIdx.x) >> 6;
  if (i >= n) return;
  const int m = min(cnt[i], CAP);
  float c0 = 0.0f, c1 = 0.0f;
  if (lane < m) {                      // lane = edge index (fully lane-parallel)
    int v = jw[(size_t)i * CAP + lane];
    int j = min(v & 0x7FFF, n - 1);
    int p = (v >> 15) & 7;
    float w0 = (float)((unsigned)v >> 18) * (1.0f / 16383.0f);
    float w1 = 1.0f - w0;
    const float* tb = T + (size_t)j * 16 + p * 2;
    float2 ta = *(const float2*)(tb);
    float2 tc = *(const float2*)(tb + 2);
    c0 = w0 * ta.x + w1 * tc.x;
    c1 = w0 * ta.y + w1 * tc.y;
  }
  // linear path: lane = channel
  float xi = b2f(Xb[(size_t)i * 64 + lane]);
  float2 fw = *(const float2*)(fW3 + lane * 2);
  c0 = fmaf(xi, fw.x, c0);
  c1 = fmaf(xi, fw.y, c1);
  #pragma unroll
  for (int off = 32; off > 0; off >>= 1) {
    c0 += __shfl_xor(c0, off, 64);
    c1 += __shfl_xor(c1, off, 64);
  }
  if (lane == 0) {
    out[(size_t)i * 2 + 0] = c0 + cb3[0] + fb3[0];
    out[(size_t)i * 2 + 1] = c1 + cb3[1] + fb3[1];
  }
}

extern "C" void kernel_launch(void* const* d_in, const int* in_sizes, int n_in,
                              void* d_out, int out_size, void* d_ws, size_t ws_size,
                              hipStream_t stream) {
  const float* X    = (const float*)d_in[0];
  const int*   fi   = (const int*)d_in[1];
  const int*   fj   = (const int*)d_in[2];
  const float* dist = (const float*)d_in[3];
  const float* cW0 = (const float*)d_in[4];  const float* cb0 = (const float*)d_in[5];
  const float* fW0 = (const float*)d_in[6];  const float* fb0 = (const float*)d_in[7];
  const float* cW1 = (const float*)d_in[8];  const float* cb1 = (const float*)d_in[9];
  const float* fW1 = (const float*)d_in[10]; const float* fb1 = (const float*)d_in[11];
  const float* cW2 = (const float*)d_in[12]; const float* cb2 = (const float*)d_in[13];
  const float* fW2 = (const float*)d_in[14]; const float* fb2 = (const float*)d_in[15];
  const float* cW3 = (const float*)d_in[16]; const float* cb3 = (const float*)d_in[17];
  const float* fW3 = (const float*)d_in[18]; const float* fb3 = (const float*)d_in[19];
  float* out = (float*)d_out;

  const int n  = in_sizes[0] / 4;  // N = 30000
  const int nE = in_sizes[1];      // E = 480000

  // workspace (~75 MB): UL bf16[n*576] | ansc2 bf16[n*64] | ansc1 bf16[n*64]
  //   | ans1 fp32[n*64] | T fp32[n*16] | wtul1 | wtul2 | jw[n*CAP] | cnt[n] | U0 bf16[n*288]
  unsigned short* UL    = (unsigned short*)d_ws;
  unsigned short* ansc2 = UL + (size_t)n * 576;     // conv2 output (layer3 input)
  unsigned short* ansc1 = ansc2 + (size_t)n * 64;
  float*          ans1  = (float*)(ansc1 + (size_t)n * 64);
  float* T     = ans1 + (size_t)n * 64;
  short* wtul1 = (short*)(T + (size_t)n * 16);
  short* wtul2 = wtul1 + 576 * 64;
  int*   jw    = (int*)(wtul2 + 576 * 64);
  int*   cnt   = jw + (size_t)n * CAP;
  unsigned short* U0 = (unsigned short*)(cnt + n);  // [n,288]

  hipMemsetAsync(cnt, 0, (size_t)n * sizeof(int), stream);
  const int fillBlocks = (nE + 255) / 256;
  const int prepBlocks = (2 * 576 * 64 + 255) / 256;
  const int u0Blocks   = (n * 288 + 255) / 256;
  fill_prep<<<fillBlocks + prepBlocks + u0Blocks, 256, 0, stream>>>(
      dist, fi, fj, cnt, jw, nE, cW1, fW1, cW2, fW2, wtul1, wtul2,
      X, cW0, fW0, U0, n, fillBlocks, prepBlocks);

  // layer 0 + gemm_ul layer 1 (fused; pair-packed U0 gather, no atomics)
  layer0_gemm<<<(n + 15) / 16, 1024, 0, stream>>>(U0, cnt, jw, cb0, fb0,
                                                  wtul1, UL, n);
  // layer 1 conv
  conv_gather<false, true, false><<<(n * 64 + 255) / 256, 256, 0, stream>>>(
      UL, cnt, jw, cb1, fb1, nullptr, nullptr, nullptr, ans1, ansc1, n);
  // layer 2
  gemm_ul<<<(n + 15) / 16, 256, 0, stream>>>(ansc1, wtul2, UL, n);
  conv_gather<true, false, true><<<(n * 64 + 255) / 256, 256, 0, stream>>>(
      UL, cnt, jw, cb2, fb2, ans1, cW3, T, nullptr, ansc2, n);
  // layer 3
  layer3_kernel<<<(n * 64 + 255) / 256, 256, 0, stream>>>(ansc2, T, cnt, jw,
                                                          cb3, fb3, fW3, out, n);
}

// Round 20
// 249.981 us; speedup vs baseline: 1.0450x; 1.0450x over previous
//
#include <hip/hip_runtime.h>

// RbfNet on MI355X — round 20:
// (a) conv1 + gemm_ul2 FUSED (node-local dependency, like r17's layer0+gemm_ul1):
//     conv_gemm = 1024-thread blocks, 16 waves = 16 nodes; per-wave gather identical
//     to conv_gather (proven memory-floor shape), epilogue -> ans1 + LDS bf16 row,
//     then 16x576 MFMA tail writes UL2. Kills the gemm_ul dispatch + ansc1 round-trip.
//     UL double-buffered (A/B); U0 aliases UL_B (dead after layer0_gemm). ws ~88.6MB.
// (b) U0 prep vectorized: 4 channels/thread (shared p), uint2 stores — r19's U0 range
//     burned ~15us on per-1-channel decode overhead.
// Structure: UL[j] = [x_j @ cW (p-major, 512) | x_j @ fW (64)]; conv(x)[i] =
// sum_e w0*U[j,p] + w1*U[j,p+1]; layer3 via T[j][p] = ansc2[j] @ cW3[p] (fused in conv2).
// Edge record (4B): j(15b) | p(3b) | round(w0*16383)(14b); w1 = 1-w0. Self-edges dropped.

#define CAP 48

typedef __attribute__((ext_vector_type(8))) short short8;
typedef __attribute__((ext_vector_type(4))) short short4v;
typedef __attribute__((ext_vector_type(4))) float f32x4;

__device__ __forceinline__ short bf16s(float f) {   // fp32 -> bf16 RNE
  unsigned u = __float_as_uint(f);
  return (short)((u + 0x7FFF + ((u >> 16) & 1)) >> 16);
}
__device__ __forceinline__ float b2f(unsigned short s) {
  return __uint_as_float(((unsigned)s) << 16);
}
__device__ __forceinline__ unsigned pack2(float a, float b) {
  return (unsigned)(unsigned short)bf16s(a) | ((unsigned)(unsigned short)bf16s(b) << 16);
}

// ---------- fused: edge-bucket build | WTul prep | U0L0 prep (3 block ranges) ----------
__global__ void fill_prep(const float* __restrict__ dist,
                          const int* __restrict__ fi, const int* __restrict__ fj,
                          int* __restrict__ cnt, int* __restrict__ jw, int nE,
                          const float* __restrict__ cW1, const float* __restrict__ fW1,
                          const float* __restrict__ cW2, const float* __restrict__ fW2,
                          short* __restrict__ wt1, short* __restrict__ wt2,
                          const float* __restrict__ X,    // [n,4]
                          const float* __restrict__ cW0,  // [8,4,32]
                          const float* __restrict__ fW0,  // [4,32]
                          unsigned short* __restrict__ U0, int n,
                          int fillBlocks, int prepBlocks) {
  if ((int)blockIdx.x < fillBlocks) {
    int e = blockIdx.x * blockDim.x + threadIdx.x;
    if (e >= nE) return;
    int i = fi[e], j = fj[e];
    if (i == j) return;                  // centerIgnore
    float d = fminf(1.0f, fmaxf(-1.0f, dist[e]));
    float u = (d + 1.0f) * 3.5f;         // hat centers: spacing 2/7
    int p = min((int)u, 6);
    float w0 = 1.0f - (u - (float)p);
    int wq = (int)(w0 * 16383.0f + 0.5f);
    int pos = atomicAdd(&cnt[i], 1);
    if (pos < CAP)
      jw[(size_t)i * CAP + pos] = j | (p << 15) | (wq << 18);
  } else if ((int)blockIdx.x < fillBlocks + prepBlocks) {
    int idx = ((int)blockIdx.x - fillBlocks) * blockDim.x + threadIdx.x;
    if (idx >= 2 * 576 * 64) return;
    int sel = idx / (576 * 64);
    int r = idx - sel * (576 * 64);
    int col = r >> 6, ch = r & 63;
    const float* cW = sel ? cW2 : cW1;
    const float* fW = sel ? fW2 : fW1;
    float v;
    if (col < 512) {
      int p = col >> 6, co = col & 63;
      v = cW[((size_t)p * 64 + ch) * 64 + co];
    } else {
      v = fW[(size_t)ch * 64 + (col - 512)];
    }
    (sel ? wt2 : wt1)[(size_t)col * 64 + ch] = bf16s(v);
  } else {
    // U0L0: [n,288] bf16, 4 channels/thread (groups of 4 never cross a p boundary)
    int idx = ((int)blockIdx.x - fillBlocks - prepBlocks) * blockDim.x + threadIdx.x;
    if (idx >= n * 72) return;
    int i = idx / 72, g = idx - i * 72;
    float4 x = *(const float4*)(X + (size_t)i * 4);
    float xk[4] = {x.x, x.y, x.z, x.w};
    float s[4] = {0, 0, 0, 0};
    if (g < 64) {                        // conv: p = g>>3, channels (g*4)&31 ..+3
      int p = g >> 3;
      int co = (g * 4) & 31;
      #pragma unroll
      for (int k = 0; k < 4; ++k) {
        const float* wr = cW0 + ((size_t)p * 4 + k) * 32 + co;
        #pragma unroll
        for (int c = 0; c < 4; ++c) s[c] = fmaf(xk[k], wr[c], s[c]);
      }
    } else {                             // lin: channels (g-64)*4 ..+3
      int co = (g - 64) * 4;
      #pragma unroll
      for (int k = 0; k < 4; ++k) {
        const float* wr = fW0 + (size_t)k * 32 + co;
        #pragma unroll
        for (int c = 0; c < 4; ++c) s[c] = fmaf(xk[k], wr[c], s[c]);
      }
    }
    uint2 pk = make_uint2(pack2(s[0], s[1]), pack2(s[2], s[3]));
    *(uint2*)(U0 + (size_t)i * 288 + g * 4) = pk;
  }
}

// ---------- FUSED layer0 + gemm_ul1: 1024 threads, wave-per-node, no atomics ----------
__global__ __launch_bounds__(1024) void layer0_gemm(
    const unsigned short* __restrict__ U0,  // [n,288] bf16 (p-major conv ++ lin)
    const int* __restrict__ cnt, const int* __restrict__ jw,
    const float* __restrict__ cb0, const float* __restrict__ fb0,
    const short* __restrict__ WTul,   // [576,64] bf16 layer-1 weights (L2-resident)
    unsigned short* __restrict__ UL, int n) {
  __shared__ __align__(16) unsigned short sXa[16 * 64];   // ansc0 tile, bf16
  __shared__ __align__(16) short sUL[16 * 584];           // UL staging
  const int tid = threadIdx.x;
  const int w = tid >> 6;                 // wave 0..15, owns node w
  const int lane = tid & 63;
  const int grp = lane >> 5;              // 0: even edges, 1: odd edges
  const int gl = lane & 31;               // uint index within the 128B span
  const int nodeBase = blockIdx.x * 16;
  const int i = nodeBase + w;
  const bool valid = (i < n);
  const int ic = valid ? i : 0;

  int rec = jw[(size_t)ic * CAP + (lane < CAP ? lane : 0)];
  const int m = valid ? min(cnt[ic], CAP) : 0;
  const int mc = m - 1;
  float accLo = 0.0f, accHi = 0.0f;
  for (int q0 = 0; q0 < m; q0 += 16) {    // 16 edges per round, 2 per load slot
    unsigned raw[8];
    float ws[8];
    #pragma unroll
    for (int k = 0; k < 8; ++k) {         // issue all 8 loads before consuming
      int eA = q0 + 2 * k;
      int vA = __builtin_amdgcn_readlane(rec, min(eA, mc));
      int vB = __builtin_amdgcn_readlane(rec, min(eA + 1, mc));
      int v = grp ? vB : vA;
      int j = v & 0x7FFF;
      int p = (v >> 15) & 7;
      float w0 = (float)((unsigned)v >> 18) * (1.0f / 16383.0f);
      float wgt = (gl < 16) ? w0 : (1.0f - w0);
      ws[k] = (eA + grp < m) ? wgt : 0.0f;
      raw[k] = ((const unsigned*)(U0 + (size_t)j * 288 + p * 32))[gl];
    }
    #pragma unroll
    for (int k = 0; k < 8; ++k) {
      accLo = fmaf(ws[k], __uint_as_float(raw[k] << 16), accLo);
      accHi = fmaf(ws[k], __uint_as_float(raw[k] & 0xFFFF0000u), accHi);
    }
  }
  accLo += __shfl_xor(accLo, 16, 64);     // merge u0/u1 roles
  accHi += __shfl_xor(accHi, 16, 64);
  accLo += __shfl_xor(accLo, 32, 64);     // merge even/odd edge groups
  accHi += __shfl_xor(accHi, 32, 64);
  if (lane < 16) {                        // lane l holds conv ch-pair (2l, 2l+1)
    const int l = lane;
    float c0v = fmaxf(accLo + cb0[2 * l], 0.0f);
    float c1v = fmaxf(accHi + cb0[2 * l + 1], 0.0f);
    unsigned lr = ((const unsigned*)(U0 + (size_t)ic * 288 + 256))[l];
    float l0 = fmaxf(__uint_as_float(lr << 16) + fb0[2 * l], 0.0f);
    float l1 = fmaxf(__uint_as_float(lr & 0xFFFF0000u) + fb0[2 * l + 1], 0.0f);
    unsigned* row = (unsigned*)(sXa + w * 64);
    row[l] = pack2(l0, l1);
    row[16 + l] = pack2(c0v, c1v);
  }
  __syncthreads();

  // ---- gemm tile: UL[16,576] = sXa[16,64] @ WTul^T; wave w does tiles w, w+16, w+32
  const int mrow = lane & 15;
  const int quad = lane >> 4;
  short8 b0 = *(const short8*)(sXa + mrow * 64 + quad * 8);
  short8 b1 = *(const short8*)(sXa + mrow * 64 + quad * 8 + 32);
  for (int t = w; t < 36; t += 16) {
    const short* aBase = WTul + (size_t)(t * 16 + mrow) * 64 + quad * 8;
    short8 a0 = *(const short8*)(aBase);
    short8 a1 = *(const short8*)(aBase + 32);
    f32x4 acc = {0, 0, 0, 0};
    acc = __builtin_amdgcn_mfma_f32_16x16x32_bf16(a0, b0, acc, 0, 0, 0);
    acc = __builtin_amdgcn_mfma_f32_16x16x32_bf16(a1, b1, acc, 0, 0, 0);
    short4v pk;
    #pragma unroll
    for (int reg = 0; reg < 4; ++reg) pk[reg] = bf16s(acc[reg]);
    *(short4v*)(sUL + mrow * 584 + t * 16 + quad * 4) = pk;
  }
  __syncthreads();
  const int r = tid >> 6;
  const int c0 = tid & 63;
  if (nodeBase + r < n) {
    unsigned short* dst = UL + (size_t)(nodeBase + r) * 576;
    #pragma unroll
    for (int chunk = c0; chunk < 72; chunk += 64)
      *(short8*)(dst + chunk * 8) = *(const short8*)(sUL + r * 584 + chunk * 8);
  }
}

// ---------- FUSED conv1 + gemm_ul2: 1024 threads, 16 waves = 16 nodes ----------
// Per-wave gather identical to conv_gather (memory-floor shape); epilogue writes
// ans1 (fp32) + relu'd bf16 row to LDS; MFMA tail writes UL2. No ansc1 buffer.
__global__ __launch_bounds__(1024) void conv_gemm(
    const unsigned short* __restrict__ ULA, // [n,576] bf16 (layer-1 U/L)
    const int* __restrict__ cnt, const int* __restrict__ jw,
    const float* __restrict__ cb, const float* __restrict__ fb,
    const short* __restrict__ WTul2,        // [576,64] bf16 layer-2 weights
    float* __restrict__ outAns,             // ans1 fp32 [n,64] (resid for conv2)
    unsigned short* __restrict__ ULB, int n) {
  __shared__ __align__(16) unsigned short sXa[16 * 64];   // ansc1 tile, bf16
  __shared__ __align__(16) short sUL[16 * 584];           // UL2 staging
  const int tid = threadIdx.x;
  const int w = tid >> 6;
  const int lane = tid & 63;
  const int half = lane >> 5;               // 0 -> u0 (w0), 1 -> u1 (w1)
  const int pl = lane & 31;
  const int nodeBase = blockIdx.x * 16;
  const int i = nodeBase + w;
  const bool valid = (i < n);
  const int ic = valid ? i : 0;

  int rec = jw[(size_t)ic * CAP + (lane < CAP ? lane : 0)];
  const int m = valid ? min(cnt[ic], CAP) : 0;
  const int mc = m - 1;
  const unsigned Lraw = ((const unsigned*)(ULA + (size_t)ic * 576 + 512))[pl];
  float accLo = 0.0f, accHi = 0.0f;
  for (int q0 = 0; q0 < m; q0 += 16) {
    unsigned raw[16];
    float w0s[16];
    #pragma unroll
    for (int k = 0; k < 16; ++k) {          // issue all 16 loads before consuming
      int v = __builtin_amdgcn_readlane(rec, min(q0 + k, mc));
      int j = v & 0x7FFF;
      int p = (v >> 15) & 7;
      w0s[k] = (float)((unsigned)v >> 18) * (1.0f / 16383.0f);
      raw[k] = ((const unsigned*)(ULA + (size_t)j * 576 + p * 64))[lane];
    }
    #pragma unroll
    for (int k = 0; k < 16; ++k) {
      bool ok = (q0 + k < m);
      float wv = half ? (1.0f - w0s[k]) : w0s[k];
      wv = ok ? wv : 0.0f;
      accLo = fmaf(wv, __uint_as_float(raw[k] << 16), accLo);
      accHi = fmaf(wv, __uint_as_float(raw[k] & 0xFFFF0000u), accHi);
    }
  }
  accLo += __shfl_xor(accLo, 32, 64);       // merge u0/u1 halves
  accHi += __shfl_xor(accHi, 32, 64);
  if (half == 0) {                          // lanes 0-31: epilogue
    unsigned* row = (unsigned*)(sXa + w * 64);
    if (valid) {
      const int c0i = 2 * pl, c1i = c0i + 1;
      float o0 = accLo + __uint_as_float(Lraw << 16) + cb[c0i] + fb[c0i];
      float o1 = accHi + __uint_as_float(Lraw & 0xFFFF0000u) + cb[c1i] + fb[c1i];
      *(float2*)(outAns + (size_t)i * 64 + c0i) = make_float2(o0, o1);
      row[pl] = pack2(fmaxf(o0, 0.0f), fmaxf(o1, 0.0f));
    } else {
      row[pl] = 0u;
    }
  }
  __syncthreads();

  // ---- gemm tile: UL2[16,576] = sXa[16,64] @ WTul2^T
  const int mrow = lane & 15;
  const int quad = lane >> 4;
  short8 b0 = *(const short8*)(sXa + mrow * 64 + quad * 8);
  short8 b1 = *(const short8*)(sXa + mrow * 64 + quad * 8 + 32);
  for (int t = w; t < 36; t += 16) {
    const short* aBase = WTul2 + (size_t)(t * 16 + mrow) * 64 + quad * 8;
    short8 a0 = *(const short8*)(aBase);
    short8 a1 = *(const short8*)(aBase + 32);
    f32x4 acc = {0, 0, 0, 0};
    acc = __builtin_amdgcn_mfma_f32_16x16x32_bf16(a0, b0, acc, 0, 0, 0);
    acc = __builtin_amdgcn_mfma_f32_16x16x32_bf16(a1, b1, acc, 0, 0, 0);
    short4v pk;
    #pragma unroll
    for (int reg = 0; reg < 4; ++reg) pk[reg] = bf16s(acc[reg]);
    *(short4v*)(sUL + mrow * 584 + t * 16 + quad * 4) = pk;
  }
  __syncthreads();
  const int r = tid >> 6;
  const int c0 = tid & 63;
  if (nodeBase + r < n) {
    unsigned short* dst = ULB + (size_t)(nodeBase + r) * 576;
    #pragma unroll
    for (int chunk = c0; chunk < 72; chunk += 64)
      *(short8*)(dst + chunk * 8) = *(const short8*)(sUL + r * 584 + chunk * 8);
  }
}

// ---------- conv2: wave per node; gather + resid + fused T ----------
__global__ __launch_bounds__(256) void conv2_kernel(
    const unsigned short* __restrict__ UL,  // ULB [n,576] bf16
    const int* __restrict__ cnt, const int* __restrict__ jw,
    const float* __restrict__ cb, const float* __restrict__ fb,
    const float* __restrict__ resid,        // ans1 fp32 [n,64]
    const float* __restrict__ cW3,          // [8,64,2]
    float* __restrict__ T,                  // [n,16] fp32
    unsigned short* __restrict__ outAnsc, int n) {  // ansc2 bf16 [n,64]
  const int lane = threadIdx.x & 63;
  const int half = lane >> 5;
  const int pl = lane & 31;
  const int i = (blockIdx.x * blockDim.x + threadIdx.x) >> 6;
  if (i >= n) return;
  int rec = jw[(size_t)i * CAP + (lane < CAP ? lane : 0)];
  const int m = min(cnt[i], CAP);
  const int mc = m - 1;
  const unsigned Lraw = ((const unsigned*)(UL + (size_t)i * 576 + 512))[pl];
  float2 rv = *(const float2*)(resid + (size_t)i * 64 + 2 * pl);
  float accLo = 0.0f, accHi = 0.0f;
  for (int q0 = 0; q0 < m; q0 += 16) {
    unsigned raw[16];
    float w0s[16];
    #pragma unroll
    for (int k = 0; k < 16; ++k) {
      int v = __builtin_amdgcn_readlane(rec, min(q0 + k, mc));
      int j = v & 0x7FFF;
      int p = (v >> 15) & 7;
      w0s[k] = (float)((unsigned)v >> 18) * (1.0f / 16383.0f);
      raw[k] = ((const unsigned*)(UL + (size_t)j * 576 + p * 64))[lane];
    }
    #pragma unroll
    for (int k = 0; k < 16; ++k) {
      bool ok = (q0 + k < m);
      float wv = half ? (1.0f - w0s[k]) : w0s[k];
      wv = ok ? wv : 0.0f;
      accLo = fmaf(wv, __uint_as_float(raw[k] << 16), accLo);
      accHi = fmaf(wv, __uint_as_float(raw[k] & 0xFFFF0000u), accHi);
    }
  }
  accLo += __shfl_xor(accLo, 32, 64);
  accHi += __shfl_xor(accHi, 32, 64);
  if (half == 0) {
    const int c0i = 2 * pl, c1i = c0i + 1;
    float o0 = accLo + __uint_as_float(Lraw << 16) + cb[c0i] + fb[c0i] + rv.x;
    float o1 = accHi + __uint_as_float(Lraw & 0xFFFF0000u) + cb[c1i] + fb[c1i] + rv.y;
    unsigned short xb0 = (unsigned short)bf16s(fmaxf(o0, 0.0f));
    unsigned short xb1 = (unsigned short)bf16s(fmaxf(o1, 0.0f));
    ((unsigned*)(outAnsc + (size_t)i * 64))[pl] = (unsigned)xb0 | ((unsigned)xb1 << 16);
    // fused T: T[i][t] = sum_ch ansc2[i,ch] * cW3[t>>1][ch][t&1]
    float x0 = b2f(xb0), x1 = b2f(xb1);
    float c[16];
    #pragma unroll
    for (int t = 0; t < 16; ++t) {
      const float* wrow = cW3 + ((size_t)(t >> 1) * 64) * 2 + (t & 1);
      c[t] = x0 * wrow[c0i * 2] + x1 * wrow[c1i * 2];
    }
    #pragma unroll
    for (int off = 16; off > 0; off >>= 1) {
      #pragma unroll
      for (int t = 0; t < 16; ++t) c[t] += __shfl_xor(c[t], off, 64);
    }
    if (pl == 0) {
      float* tr = T + (size_t)i * 16;
      #pragma unroll
      for (int t = 0; t < 16; ++t) tr[t] = c[t];
    }
  }
}

// ---------- layer 3: wave per node, lane = edge; 16B/edge from T; + lin; reduce ----------
__global__ __launch_bounds__(256, 4) void layer3_kernel(
    const unsigned short* __restrict__ Xb,  // ansc2 [n,64] bf16
    const float* __restrict__ T,            // [n,16] fp32
    const int* __restrict__ cnt, const int* __restrict__ jw,
    const float* __restrict__ cb3, const float* __restrict__ fb3,
    const float* __restrict__ fW3,          // [64,2]
    float* __restrict__ out, int n) {
  const int lane = threadIdx.x & 63;
  const int i = (blockIdx.x * blockDim.x + threadIdx.x) >> 6;
  if (i >= n) return;
  const int m = min(cnt[i], CAP);
  float c0 = 0.0f, c1 = 0.0f;
  if (lane < m) {                      // lane = edge index (fully lane-parallel)
    int v = jw[(size_t)i * CAP + lane];
    int j = min(v & 0x7FFF, n - 1);
    int p = (v >> 15) & 7;
    float w0 = (float)((unsigned)v >> 18) * (1.0f / 16383.0f);
    float w1 = 1.0f - w0;
    const float* tb = T + (size_t)j * 16 + p * 2;
    float2 ta = *(const float2*)(tb);
    float2 tc = *(const float2*)(tb + 2);
    c0 = w0 * ta.x + w1 * tc.x;
    c1 = w0 * ta.y + w1 * tc.y;
  }
  float xi = b2f(Xb[(size_t)i * 64 + lane]);
  float2 fw = *(const float2*)(fW3 + lane * 2);
  c0 = fmaf(xi, fw.x, c0);
  c1 = fmaf(xi, fw.y, c1);
  #pragma unroll
  for (int off = 32; off > 0; off >>= 1) {
    c0 += __shfl_xor(c0, off, 64);
    c1 += __shfl_xor(c1, off, 64);
  }
  if (lane == 0) {
    out[(size_t)i * 2 + 0] = c0 + cb3[0] + fb3[0];
    out[(size_t)i * 2 + 1] = c1 + cb3[1] + fb3[1];
  }
}

extern "C" void kernel_launch(void* const* d_in, const int* in_sizes, int n_in,
                              void* d_out, int out_size, void* d_ws, size_t ws_size,
                              hipStream_t stream) {
  const float* X    = (const float*)d_in[0];
  const int*   fi   = (const int*)d_in[1];
  const int*   fj   = (const int*)d_in[2];
  const float* dist = (const float*)d_in[3];
  const float* cW0 = (const float*)d_in[4];  const float* cb0 = (const float*)d_in[5];
  const float* fW0 = (const float*)d_in[6];  const float* fb0 = (const float*)d_in[7];
  const float* cW1 = (const float*)d_in[8];  const float* cb1 = (const float*)d_in[9];
  const float* fW1 = (const float*)d_in[10]; const float* fb1 = (const float*)d_in[11];
  const float* cW2 = (const float*)d_in[12]; const float* cb2 = (const float*)d_in[13];
  const float* fW2 = (const float*)d_in[14]; const float* fb2 = (const float*)d_in[15];
  const float* cW3 = (const float*)d_in[16]; const float* cb3 = (const float*)d_in[17];
  const float* fW3 = (const float*)d_in[18]; const float* fb3 = (const float*)d_in[19];
  float* out = (float*)d_out;

  const int n  = in_sizes[0] / 4;  // N = 30000
  const int nE = in_sizes[1];      // E = 480000

  // workspace (~88.6 MB):
  //   ULA bf16[n*576] | ULB bf16[n*576] (U0[n*288] aliases its start; dead after layer0)
  // | ans1 fp32[n*64] | ansc2 bf16[n*64] | T fp32[n*16] | wt1 | wt2 | jw[n*CAP] | cnt[n]
  unsigned short* ULA   = (unsigned short*)d_ws;
  unsigned short* ULB   = ULA + (size_t)n * 576;
  unsigned short* U0    = ULB;                      // alias (dead after layer0_gemm)
  float*          ans1  = (float*)(ULB + (size_t)n * 576);
  unsigned short* ansc2 = (unsigned short*)(ans1 + (size_t)n * 64);
  float* T     = (float*)(ansc2 + (size_t)n * 64);
  short* wtul1 = (short*)(T + (size_t)n * 16);
  short* wtul2 = wtul1 + 576 * 64;
  int*   jw    = (int*)(wtul2 + 576 * 64);
  int*   cnt   = jw + (size_t)n * CAP;

  hipMemsetAsync(cnt, 0, (size_t)n * sizeof(int), stream);
  const int fillBlocks = (nE + 255) / 256;
  const int prepBlocks = (2 * 576 * 64 + 255) / 256;
  const int u0Blocks   = (n * 72 + 255) / 256;
  fill_prep<<<fillBlocks + prepBlocks + u0Blocks, 256, 0, stream>>>(
      dist, fi, fj, cnt, jw, nE, cW1, fW1, cW2, fW2, wtul1, wtul2,
      X, cW0, fW0, U0, n, fillBlocks, prepBlocks);

  // layer 0 + gemm_ul1 (reads U0=ULB region, writes ULA)
  layer0_gemm<<<(n + 15) / 16, 1024, 0, stream>>>(U0, cnt, jw, cb0, fb0,
                                                  wtul1, ULA, n);
  // conv1 + gemm_ul2 (reads ULA, writes ans1 + ULB)
  conv_gemm<<<(n + 15) / 16, 1024, 0, stream>>>(ULA, cnt, jw, cb1, fb1,
                                                wtul2, ans1, ULB, n);
  // conv2 (+resid +fused T) (reads ULB, ans1; writes ansc2, T)
  conv2_kernel<<<(n * 64 + 255) / 256, 256, 0, stream>>>(
      ULB, cnt, jw, cb2, fb2, ans1, cW3, T, ansc2, n);
  // layer 3
  layer3_kernel<<<(n * 64 + 255) / 256, 256, 0, stream>>>(ansc2, T, cnt, jw,
                                                          cb3, fb3, fW3, out, n);
}